// Round 1
// baseline (454.583 us; speedup 1.0000x reference)
//
#include <hip/hip_runtime.h>
#include <hip/hip_bf16.h>
#include <math.h>

#define B_   2048
#define N_   38
#define E_   4
#define DIN_ 9
#define H0_  256
#define H1_  256
#define L0_  512
#define M_   (B_ * N_)

typedef short bf16x8 __attribute__((ext_vector_type(8)));
typedef float f32x4 __attribute__((ext_vector_type(4)));

// ---------- bf16 helpers ----------
__device__ __forceinline__ float b2f(unsigned short u) {
  return __uint_as_float((unsigned)u << 16);
}
__device__ __forceinline__ unsigned short f2b(float f) {
  __hip_bfloat16 h = __float2bfloat16(f);
  return *(unsigned short*)&h;
}

// reduce over 16 consecutive lanes (lrow dimension)
__device__ __forceinline__ float rsum16(float v) {
  v += __shfl_xor(v, 1);
  v += __shfl_xor(v, 2);
  v += __shfl_xor(v, 4);
  v += __shfl_xor(v, 8);
  return v;
}

// Wg0 bf16 [256 c][96 k]: k<64 -> z-part (e=k>>4,f=k&15: f<9 We0[(c*4+e)][f], f==9 be0[c*4+e]);
// k in [64,80) -> x-part (f=k-64: f<9 Ws0[c][f], f==9 bs0[c]); else 0.
__global__ void k_build_wg0(const float* __restrict__ Ws, const float* __restrict__ bs,
                            const float* __restrict__ We, const float* __restrict__ be,
                            unsigned short* __restrict__ WT) {
  int i = blockIdx.x * 256 + threadIdx.x;
  if (i >= 256 * 96) return;
  int c = i / 96, k = i % 96;
  float v = 0.f;
  if (k < 64) {
    int e = k >> 4, f = k & 15;
    if (f < 9) v = We[(c * 4 + e) * 9 + f];
    else if (f == 9) v = be[c * 4 + e];
  } else if (k < 80) {
    int f = k - 64;
    if (f < 9) v = Ws[c * 9 + f];
    else if (f == 9) v = bs[c];
  }
  WT[i] = f2b(v);
}

// Wcat bf16 [256 c][1280 k]: k<256 -> Ws1[c][k]; k>=256: e=(k-256)>>8, f=(k-256)&255 -> We1[(c*4+e)][f]
__global__ void k_build_wcat(const float* __restrict__ Ws, const float* __restrict__ We,
                             unsigned short* __restrict__ WT) {
  int i = blockIdx.x * 256 + threadIdx.x;
  if (i >= 256 * 1280) return;
  int c = i / 1280, k = i % 1280;
  float v;
  if (k < 256) v = Ws[c * 256 + k];
  else { int kk = k - 256; int e = kk >> 8, f = kk & 255; v = We[(c * 4 + e) * 256 + f]; }
  WT[i] = f2b(v);
}

// Wl bf16 [512][256]
__global__ void k_build_wl(const float* __restrict__ W, unsigned short* __restrict__ WT) {
  int i = blockIdx.x * 256 + threadIdx.x;
  if (i >= 512 * 256) return;
  WT[i] = f2b(W[i]);
}

// Wfb bf16 [32][512]
__global__ void k_build_wf(const float* __restrict__ W, unsigned short* __restrict__ WT) {
  int i = blockIdx.x * 256 + threadIdx.x;
  if (i >= 32 * 512) return;
  int r = i / 512, k = i % 512;
  WT[i] = f2b(r < 18 ? W[r * 512 + k] : 0.f);
}

// partials reduce: part[nblk][76] -> st
__global__ __launch_bounds__(256) void k_gred(const float* __restrict__ part, int nblk,
                                              float* __restrict__ st) {
  const int j = blockIdx.x, tid = threadIdx.x;
  float s = 0.f;
  for (int i = tid; i < nblk; i += 256) s += part[(size_t)i * 76 + j];
#pragma unroll
  for (int off = 32; off; off >>= 1) s += __shfl_down(s, off);
  __shared__ float r[4];
  if ((tid & 63) == 0) r[tid >> 6] = s;
  __syncthreads();
  if (tid == 0) {
    float tot = r[0] + r[1] + r[2] + r[3];
    if (j < 38) st[j * 2] = tot;
    else st[(j - 38) * 2 + 1] = tot;
  }
}

// ---------------- gconv layer 0, full MFMA (z + main GEMM), bias/be folded into Wg0 ----------------
__global__ __launch_bounds__(256) void k_gconv0(
    const float* __restrict__ adj, const float* __restrict__ x,
    const unsigned short* __restrict__ Wg0, unsigned short* __restrict__ g,
    float* __restrict__ part) {
  __shared__ __align__(16) unsigned short adjB[4 * 48 * 64];  // [e][m(48)][n(64)] 24.6KB
  __shared__ __align__(16) unsigned short zB[48 * 64];        // [m][e*16+f] 6KB
  __shared__ __align__(16) unsigned short xLA[64 * 32];       // [m][f(32)] 4KB (A chunk2)
  __shared__ __align__(16) unsigned short xLB[16 * 64];       // [f][n(64)] 2KB (B of z-mfma)
  __shared__ float lsumW[4][48], lsqW[4][48];
  const int b = blockIdx.x, t = threadIdx.x;
  const uint4 z4 = make_uint4(0, 0, 0, 0);
  for (int i = t; i < 4 * 48 * 64 / 8; i += 256) ((uint4*)adjB)[i] = z4;
  for (int i = t; i < 64 * 32 / 8; i += 256) ((uint4*)xLA)[i] = z4;
  for (int i = t; i < 16 * 64 / 8; i += 256) ((uint4*)xLB)[i] = z4;
  __syncthreads();
  for (int i = t; i < 4 * 38 * 38; i += 256) {
    int e = i / 1444, r = i % 1444, m = r / 38, n = r % 38;
    adjB[(e * 48 + m) * 64 + n] = f2b(adj[(size_t)b * 5776 + i]);
  }
  for (int i = t; i < 342; i += 256) {
    int m = i / 9, f = i % 9;
    float v = x[(size_t)b * 342 + i];
    unsigned short bv = f2b((m & 1) ? v : 0.f);
    xLA[m * 32 + f] = bv;
    xLB[f * 64 + m] = bv;
  }
  if (t < 38) {
    unsigned short one = f2b(1.f);
    xLA[t * 32 + 9] = one;
    xLB[9 * 64 + t] = one;
  }
  __syncthreads();
  const int w = t >> 6, L = t & 63;
  const int lrow = L & 15, quad = L >> 4;
  {
    f32x4 za[3];
#pragma unroll
    for (int mt = 0; mt < 3; ++mt) za[mt] = (f32x4){0.f, 0.f, 0.f, 0.f};
#pragma unroll
    for (int kk = 0; kk < 2; ++kk) {
      bf16x8 bb = *(const bf16x8*)&xLB[lrow * 64 + kk * 32 + quad * 8];
#pragma unroll
      for (int mt = 0; mt < 3; ++mt) {
        bf16x8 aa = *(const bf16x8*)&adjB[(w * 48 + mt * 16 + lrow) * 64 + kk * 32 + quad * 8];
        za[mt] = __builtin_amdgcn_mfma_f32_16x16x32_bf16(aa, bb, za[mt], 0, 0, 0);
      }
    }
#pragma unroll
    for (int mt = 0; mt < 3; ++mt)
#pragma unroll
      for (int reg = 0; reg < 4; ++reg)
        zB[(mt * 16 + quad * 4 + reg) * 64 + w * 16 + lrow] = f2b(za[mt][reg]);
  }
  __syncthreads();
  f32x4 acc[3][4];
#pragma unroll
  for (int mt = 0; mt < 3; ++mt)
#pragma unroll
    for (int nt = 0; nt < 4; ++nt) acc[mt][nt] = (f32x4){0.f, 0.f, 0.f, 0.f};
#pragma unroll
  for (int kc = 0; kc < 3; ++kc) {
    bf16x8 af[3];
#pragma unroll
    for (int mt = 0; mt < 3; ++mt)
      af[mt] = (kc < 2)
                   ? *(const bf16x8*)&zB[(mt * 16 + lrow) * 64 + kc * 32 + quad * 8]
                   : *(const bf16x8*)&xLA[(mt * 16 + lrow) * 32 + quad * 8];
#pragma unroll
    for (int nt = 0; nt < 4; ++nt) {
      const int c = w * 64 + nt * 16 + lrow;
      bf16x8 bf_ = *(const bf16x8*)&Wg0[(size_t)c * 96 + kc * 32 + quad * 8];
#pragma unroll
      for (int mt = 0; mt < 3; ++mt)
        acc[mt][nt] = __builtin_amdgcn_mfma_f32_16x16x32_bf16(af[mt], bf_, acc[mt][nt], 0, 0, 0);
    }
  }
#pragma unroll
  for (int mt = 0; mt < 3; ++mt) {
#pragma unroll
    for (int reg = 0; reg < 4; ++reg) {
      const int m = mt * 16 + quad * 4 + reg;
      float sv = 0.f, qv = 0.f;
      if (m < N_) {
#pragma unroll
        for (int nt = 0; nt < 4; ++nt) {
          const int c = w * 64 + nt * 16 + lrow;
          float v = acc[mt][nt][reg];
          g[((size_t)b * N_ + m) * 256 + c] = f2b(v);
          sv += v;
          qv += v * v;
        }
      }
      sv = rsum16(sv);
      qv = rsum16(qv);
      if (lrow == 0) { lsumW[w][m] = sv; lsqW[w][m] = qv; }
    }
  }
  __syncthreads();
  if (t < 38) {
    part[(size_t)b * 76 + t] = lsumW[0][t] + lsumW[1][t] + lsumW[2][t] + lsumW[3][t];
    part[(size_t)b * 76 + 38 + t] = lsqW[0][t] + lsqW[1][t] + lsqW[2][t] + lsqW[3][t];
  }
}

// ---------------- fused layer 1: per-b, P-trick (adj contracted BEFORE the wide GEMM) ----------------
// h2[b,m,c] = A[b,m,:]@Ws1[c,:] + sum_e (adj_e@A)[m,:]@We1[c*4+e,:] + bs[c] + sum_e arow_e[m]*be[c*4+e]
// where A = BN0ReLU(g0[b]).  Wcat[256][1280] = [Ws1 | We1(e=0) | .. | We1(e=3)] read from L2.
__global__ __launch_bounds__(256) void k_l1f(
    const float* __restrict__ adj, const unsigned short* __restrict__ g0,
    const unsigned short* __restrict__ Wcat, const float* __restrict__ st0,
    const float* __restrict__ gam, const float* __restrict__ bet,
    const float* __restrict__ bs, const float* __restrict__ be,
    unsigned short* __restrict__ h2, float* __restrict__ part) {
  __shared__ __align__(16) unsigned short adjB[4 * 48 * 64];     // [e][m(48)][n(64)] swz by (m&7)<<4
  __shared__ __align__(16) unsigned short Abt[256 * 48 + 16];    // [c][n(48)] + overread pad
  __shared__ __align__(16) unsigned short Pbuf[48 * 256];        // [m][k(256)] swz by (m&7)<<4
  __shared__ float aS[38], bS[38];
  __shared__ float arowS[4 * 48];
  __shared__ float lsumW[4][48], lsqW[4][48];
  const int b = blockIdx.x, t = threadIdx.x;
  // ---- Phase A: zero adjB, BN0 coefficients
  for (int i = t; i < 4 * 48 * 64 / 8; i += 256) ((uint4*)adjB)[i] = make_uint4(0, 0, 0, 0);
  if (t < 38) {
    const float cnt = 2048.f * 256.f;
    float mu = st0[t * 2] / cnt;
    float var = st0[t * 2 + 1] / cnt - mu * mu;
    float a = rsqrtf(var + 1e-5f) * gam[t];
    aS[t] = a;
    bS[t] = bet[t] - mu * a;
  }
  __syncthreads();
  // ---- Phase B: stage adj (bf16, swizzled); stage A=BN0ReLU(g0) into Pbuf (row-major, swizzled)
  for (int i = t; i < 4 * 38 * 38; i += 256) {
    int e = i / 1444, r = i % 1444, m = r / 38, n = r % 38;
    *(unsigned short*)((char*)adjB + (e * 48 + m) * 128 + ((2 * n) ^ ((m & 7) << 4))) =
        f2b(adj[(size_t)b * 5776 + i]);
  }
  for (int i = t; i < 38 * 32; i += 256) {
    int n = i >> 5, seg = (i & 31) * 8;
    uint4 u = *(const uint4*)&g0[((size_t)b * N_ + n) * 256 + seg];
    float a = aS[n], bb2 = bS[n];
    unsigned* up = (unsigned*)&u;
    uint4 o;
    unsigned* op = (unsigned*)&o;
#pragma unroll
    for (int j = 0; j < 4; ++j) {
      float lo = fmaxf(fmaf(b2f((unsigned short)(up[j] & 0xffff)), a, bb2), 0.f);
      float hi = fmaxf(fmaf(b2f((unsigned short)(up[j] >> 16)), a, bb2), 0.f);
      op[j] = (unsigned)f2b(lo) | ((unsigned)f2b(hi) << 16);
    }
    *(uint4*)((char*)Pbuf + n * 512 + ((seg * 2) ^ ((n & 7) << 4))) = o;
  }
  for (int i = t; i < 10 * 32; i += 256) {
    int n = 38 + (i >> 5), seg = (i & 31) * 8;
    *(uint4*)((char*)Pbuf + n * 512 + ((seg * 2) ^ ((n & 7) << 4))) = make_uint4(0, 0, 0, 0);
  }
  __syncthreads();
  // ---- Phase C: arow sums; build Abt=[c][n] (transpose of A); hs GEMM block (K-block 0)
  if (t < 152) {
    int e = t / 38, m = t % 38;
    float s = 0.f;
    for (int n = 0; n < 38; ++n)
      s += b2f(*(const unsigned short*)((const char*)adjB + (e * 48 + m) * 128 +
                                        ((2 * n) ^ ((m & 7) << 4))));
    arowS[e * 48 + m] = s;
  }
  {
    const int c = t;  // 0..255
#pragma unroll
    for (int j = 0; j < 5; ++j) {
      uint4 o;
      unsigned* op = (unsigned*)&o;
#pragma unroll
      for (int q = 0; q < 4; ++q) {
        int n0 = j * 8 + q * 2;
        unsigned short lo = 0, hi = 0;
        if (n0 < 38)
          lo = *(const unsigned short*)((const char*)Pbuf + n0 * 512 +
                                        ((2 * c) ^ ((n0 & 7) << 4)));
        if (n0 + 1 < 38)
          hi = *(const unsigned short*)((const char*)Pbuf + (n0 + 1) * 512 +
                                        ((2 * c) ^ (((n0 + 1) & 7) << 4)));
        op[q] = (unsigned)lo | ((unsigned)hi << 16);
      }
      *(uint4*)&Abt[c * 48 + j * 8] = o;
    }
    *(uint4*)&Abt[c * 48 + 40] = make_uint4(0, 0, 0, 0);
  }
  const int w = t >> 6, L = t & 63;
  const int lrow = L & 15, quad = L >> 4;
  f32x4 acc[3][4];
#pragma unroll
  for (int mt = 0; mt < 3; ++mt)
#pragma unroll
    for (int nt = 0; nt < 4; ++nt) acc[mt][nt] = (f32x4){0.f, 0.f, 0.f, 0.f};

#define MAIN_KBLOCK(WOFF)                                                              \
  _Pragma("unroll") for (int kc = 0; kc < 8; ++kc) {                                   \
    bf16x8 af[3];                                                                      \
    _Pragma("unroll") for (int mt = 0; mt < 3; ++mt) af[mt] =                          \
        *(const bf16x8*)((const char*)Pbuf + (mt * 16 + lrow) * 512 +                  \
                         ((kc * 64 + quad * 16) ^ ((lrow & 7) << 4)));                 \
    _Pragma("unroll") for (int nt = 0; nt < 4; ++nt) {                                 \
      const int c = w * 64 + nt * 16 + lrow;                                           \
      bf16x8 bf_ = *(const bf16x8*)&Wcat[(size_t)c * 1280 + (WOFF) + kc * 32 + quad * 8]; \
      _Pragma("unroll") for (int mt = 0; mt < 3; ++mt) acc[mt][nt] =                   \
          __builtin_amdgcn_mfma_f32_16x16x32_bf16(af[mt], bf_, acc[mt][nt], 0, 0, 0);  \
    }                                                                                  \
  }

  MAIN_KBLOCK(0)  // hs block: A @ Ws1^T

  // ---- e-loop: P_e = adj_e @ A  ->  Pbuf, then K-block GEMM vs We1(e)
#pragma unroll 1
  for (int e = 0; e < 4; ++e) {
    f32x4 pa[3][4];
#pragma unroll
    for (int mt = 0; mt < 3; ++mt)
#pragma unroll
      for (int nt = 0; nt < 4; ++nt) pa[mt][nt] = (f32x4){0.f, 0.f, 0.f, 0.f};
#pragma unroll
    for (int kk = 0; kk < 2; ++kk) {
      bf16x8 bb[4];
#pragma unroll
      for (int nt = 0; nt < 4; ++nt)
        bb[nt] = *(const bf16x8*)&Abt[(w * 64 + nt * 16 + lrow) * 48 + kk * 32 + quad * 8];
#pragma unroll
      for (int mt = 0; mt < 3; ++mt) {
        bf16x8 aa = *(const bf16x8*)((const char*)adjB + (e * 48 + mt * 16 + lrow) * 128 +
                                     ((kk * 64 + quad * 16) ^ ((lrow & 7) << 4)));
#pragma unroll
        for (int nt = 0; nt < 4; ++nt)
          pa[mt][nt] = __builtin_amdgcn_mfma_f32_16x16x32_bf16(aa, bb[nt], pa[mt][nt], 0, 0, 0);
      }
    }
    __syncthreads();  // all waves done reading Pbuf (previous K-block)
#pragma unroll
    for (int mt = 0; mt < 3; ++mt)
#pragma unroll
      for (int reg = 0; reg < 4; ++reg) {
        const int m = mt * 16 + quad * 4 + reg;
#pragma unroll
        for (int nt = 0; nt < 4; ++nt) {
          const int c2 = w * 64 + nt * 16 + lrow;
          *(unsigned short*)((char*)Pbuf + m * 512 + ((2 * c2) ^ ((m & 7) << 4))) =
              f2b(pa[mt][nt][reg]);
        }
      }
    __syncthreads();  // Pbuf(e) ready
    MAIN_KBLOCK(256 + e * 256)
  }
#undef MAIN_KBLOCK

  // ---- epilogue: + bs + arow.be, store h2, stats partials
#pragma unroll
  for (int mt = 0; mt < 3; ++mt) {
#pragma unroll
    for (int reg = 0; reg < 4; ++reg) {
      const int m = mt * 16 + quad * 4 + reg;
      float sv = 0.f, qv = 0.f;
      if (m < N_) {
        float a0 = arowS[0 * 48 + m], a1 = arowS[48 + m];
        float a2 = arowS[96 + m], a3 = arowS[144 + m];
#pragma unroll
        for (int nt = 0; nt < 4; ++nt) {
          const int col = w * 64 + nt * 16 + lrow;
          float4 bev = *(const float4*)&be[col * 4];
          float v = acc[mt][nt][reg] + bs[col] +
                    a0 * bev.x + a1 * bev.y + a2 * bev.z + a3 * bev.w;
          h2[((size_t)b * N_ + m) * 256 + col] = f2b(v);
          sv += v;
          qv += v * v;
        }
      }
      sv = rsum16(sv);
      qv = rsum16(qv);
      if (lrow == 0) { lsumW[w][m] = sv; lsqW[w][m] = qv; }
    }
  }
  __syncthreads();
  if (t < 38) {
    part[(size_t)b * 76 + t] = lsumW[0][t] + lsumW[1][t] + lsumW[2][t] + lsumW[3][t];
    part[(size_t)b * 76 + 38 + t] = lsqW[0][t] + lsqW[1][t] + lsqW[2][t] + lsqW[3][t];
  }
}

// ---------------- k_gemm: 128x256 MFMA GEMM with fused BN+ReLU on A ----------------
template <bool BIAS, bool STATS>
__global__ __launch_bounds__(512) void k_gemm(
    const unsigned short* __restrict__ A0, const unsigned short* __restrict__ Bw,
    const float* __restrict__ bias, const float* __restrict__ stIn,
    const float* __restrict__ gam, const float* __restrict__ bet, float cnt,
    unsigned short* __restrict__ Cout, int Cstride, float* __restrict__ part) {
  __shared__ __align__(16) unsigned short lA[128 * 32];
  __shared__ __align__(16) unsigned short lB[256 * 32];
  __shared__ float lbias[256];
  __shared__ float lsum[38], lsq[38];
  const int t = threadIdx.x;
  const int tileM = blockIdx.x, n_base = blockIdx.y * 256;
  if (BIAS && t < 256) lbias[t] = bias[n_base + t];
  if (STATS && t < 38) { lsum[t] = 0.f; lsq[t] = 0.f; }
  const int w = t >> 6, L = t & 63;
  const int wr = w >> 2, wc = w & 3;
  const int lrow = L & 15, quad = L >> 4;
  const int srow = t >> 2, sseg = (t & 3) * 8;
  const int nA = (tileM * 128 + srow) % 38;
  float aC, bC;
  {
    float mu = stIn[nA * 2] / cnt;
    float var = stIn[nA * 2 + 1] / cnt - mu * mu;
    aC = rsqrtf(var + 1e-5f) * gam[nA];
    bC = bet[nA] - mu * aC;
  }
  const unsigned short* aRow = A0 + (size_t)(tileM * 128 + srow) * 256 + sseg;
  f32x4 acc[4][4];
#pragma unroll
  for (int mt = 0; mt < 4; ++mt)
#pragma unroll
    for (int nt = 0; nt < 4; ++nt) acc[mt][nt] = (f32x4){0.f, 0.f, 0.f, 0.f};

  uint4 u = *(const uint4*)aRow;
  for (int ki = 0; ki < 8; ++ki) {
#pragma unroll
    for (int r = 0; r < 2; ++r) {
      const unsigned short* gp = Bw + (size_t)(n_base + r * 128 + srow) * 256 + ki * 32 + sseg;
      __builtin_amdgcn_global_load_lds(
          (const __attribute__((address_space(1))) void*)gp,
          (__attribute__((address_space(3))) void*)(lB + r * 4096 + w * 512), 16, 0, 0);
    }
    uint4 un = u;
    if (ki < 7) un = *(const uint4*)(aRow + (ki + 1) * 32);
    {
      uint4 o;
      unsigned* up = (unsigned*)&u;
      unsigned* op = (unsigned*)&o;
#pragma unroll
      for (int j = 0; j < 4; ++j) {
        float lo = fmaxf(fmaf(b2f((unsigned short)(up[j] & 0xffff)), aC, bC), 0.f);
        float hi = fmaxf(fmaf(b2f((unsigned short)(up[j] >> 16)), aC, bC), 0.f);
        op[j] = (unsigned)f2b(lo) | ((unsigned)f2b(hi) << 16);
      }
      *(uint4*)&lA[srow * 32 + sseg] = o;
    }
    __syncthreads();
    bf16x8 af[4], bfr[4];
#pragma unroll
    for (int mt = 0; mt < 4; ++mt)
      af[mt] = *(const bf16x8*)&lA[(wr * 64 + mt * 16 + lrow) * 32 + quad * 8];
#pragma unroll
    for (int nt = 0; nt < 4; ++nt)
      bfr[nt] = *(const bf16x8*)&lB[(wc * 64 + nt * 16 + lrow) * 32 + quad * 8];
#pragma unroll
    for (int mt = 0; mt < 4; ++mt)
#pragma unroll
      for (int nt = 0; nt < 4; ++nt)
        acc[mt][nt] = __builtin_amdgcn_mfma_f32_16x16x32_bf16(af[mt], bfr[nt], acc[mt][nt], 0, 0, 0);
    __syncthreads();
    u = un;
  }
#pragma unroll
  for (int mt = 0; mt < 4; ++mt) {
#pragma unroll
    for (int reg = 0; reg < 4; ++reg) {
      const size_t row = (size_t)tileM * 128 + wr * 64 + mt * 16 + quad * 4 + reg;
      float sv = 0.f, qv = 0.f;
#pragma unroll
      for (int nt = 0; nt < 4; ++nt) {
        const int lcol = wc * 64 + nt * 16 + lrow;
        float v = acc[mt][nt][reg];
        if (BIAS) v += lbias[lcol];
        Cout[row * Cstride + n_base + lcol] = f2b(v);
        sv += v;
        qv += v * v;
      }
      if (STATS) {
        sv = rsum16(sv);
        qv = rsum16(qv);
        if (lrow == 0) {
          int n = (int)(row % 38);
          atomicAdd(&lsum[n], sv);
          atomicAdd(&lsq[n], qv);
        }
      }
    }
  }
  if (STATS) {
    __syncthreads();
    const int blk = blockIdx.y * gridDim.x + blockIdx.x;
    if (t < 38) {
      part[(size_t)blk * 76 + t] = lsum[t];
      part[(size_t)blk * 76 + 38 + t] = lsq[t];
    }
  }
}

// ---------------- final: MFMA 512->18 + coupling + logdet, BN2+ReLU fused ----------------
__global__ __launch_bounds__(256) void k_final(
    const unsigned short* __restrict__ g2, const float* __restrict__ x,
    const unsigned short* __restrict__ Wfb, const float* __restrict__ fb,
    const float* __restrict__ st, const float* __restrict__ gam,
    const float* __restrict__ bet, float* __restrict__ out) {
  __shared__ __align__(16) unsigned short hA[48 * 520];
  __shared__ float lgS[48 * 20];
  __shared__ float aS[N_], bS[N_], fbS[20], red[4];
  const int b = blockIdx.x, tid = threadIdx.x;
  if (tid < N_) {
    const float cnt = 2048.f * 512.f;
    float mu = st[tid * 2] / cnt;
    float var = st[tid * 2 + 1] / cnt - mu * mu;
    float a = rsqrtf(var + 1e-5f) * gam[tid];
    aS[tid] = a;
    bS[tid] = bet[tid] - mu * a;
  }
  if (tid >= 64 && tid < 82) fbS[tid - 64] = fb[tid - 64];
  __syncthreads();
  for (int i = tid; i < N_ * 64; i += 256) {
    int n = i >> 6, seg = (i & 63) * 8;
    uint4 u = *(const uint4*)&g2[((size_t)b * N_ + n) * 512 + seg];
    float a = aS[n], bb = bS[n];
    float v[8];
    v[0] = b2f((unsigned short)(u.x & 0xffff)); v[1] = b2f((unsigned short)(u.x >> 16));
    v[2] = b2f((unsigned short)(u.y & 0xffff)); v[3] = b2f((unsigned short)(u.y >> 16));
    v[4] = b2f((unsigned short)(u.z & 0xffff)); v[5] = b2f((unsigned short)(u.z >> 16));
    v[6] = b2f((unsigned short)(u.w & 0xffff)); v[7] = b2f((unsigned short)(u.w >> 16));
#pragma unroll
    for (int j = 0; j < 8; ++j) v[j] = fmaxf(fmaf(v[j], a, bb), 0.f);
    uint4 o;
    o.x = (unsigned)f2b(v[0]) | ((unsigned)f2b(v[1]) << 16);
    o.y = (unsigned)f2b(v[2]) | ((unsigned)f2b(v[3]) << 16);
    o.z = (unsigned)f2b(v[4]) | ((unsigned)f2b(v[5]) << 16);
    o.w = (unsigned)f2b(v[6]) | ((unsigned)f2b(v[7]) << 16);
    *(uint4*)&hA[n * 520 + seg] = o;
  }
  for (int i = tid; i < 10 * 64; i += 256) {
    int n = 38 + (i >> 6), seg = (i & 63) * 8;
    *(uint4*)&hA[n * 520 + seg] = make_uint4(0, 0, 0, 0);
  }
  __syncthreads();
  const int w = tid >> 6, L = tid & 63;
  const int lrow = L & 15, quad = L >> 4;
  if (w < 3) {
    f32x4 acc0 = (f32x4){0.f, 0.f, 0.f, 0.f}, acc1 = (f32x4){0.f, 0.f, 0.f, 0.f};
#pragma unroll
    for (int ki = 0; ki < 16; ++ki) {
      bf16x8 af = *(const bf16x8*)&hA[(w * 16 + lrow) * 520 + ki * 32 + quad * 8];
      bf16x8 b0 = *(const bf16x8*)&Wfb[(size_t)lrow * 512 + ki * 32 + quad * 8];
      bf16x8 b1 = *(const bf16x8*)&Wfb[(size_t)(16 + lrow) * 512 + ki * 32 + quad * 8];
      acc0 = __builtin_amdgcn_mfma_f32_16x16x32_bf16(af, b0, acc0, 0, 0, 0);
      acc1 = __builtin_amdgcn_mfma_f32_16x16x32_bf16(af, b1, acc1, 0, 0, 0);
    }
#pragma unroll
    for (int reg = 0; reg < 4; ++reg) {
      int m = w * 16 + quad * 4 + reg;
      if (m < N_) {
        lgS[m * 20 + lrow] = acc0[reg] + fbS[lrow];
        if (lrow < 2) lgS[m * 20 + 16 + lrow] = acc1[reg] + fbS[16 + lrow];
      }
    }
  }
  __syncthreads();
  float ls = 0.f;
  for (int ii = tid; ii < 342; ii += 256) {
    int mm = ii / 9, d = ii % 9;
    float sl = lgS[mm * 20 + d];
    float tv = lgS[mm * 20 + 9 + d];
    float xv = x[((size_t)b * N_ + mm) * 9 + d];
    float sg = 1.f / (1.f + expf(-sl));
    float o = (mm & 1) ? xv : (xv + tv) * sg;
    out[((size_t)b * N_ + mm) * 9 + d] = o;
    ls += (sl >= 0.f) ? -log1pf(expf(-sl)) : (sl - log1pf(expf(sl)));
  }
#pragma unroll
  for (int off = 32; off; off >>= 1) ls += __shfl_down(ls, off);
  if (L == 0) red[w] = ls;
  __syncthreads();
  if (tid == 0) out[(size_t)B_ * 342 + b] = red[0] + red[1] + red[2] + red[3];
}

extern "C" void kernel_launch(void* const* d_in, const int* in_sizes, int n_in,
                              void* d_out, int out_size, void* d_ws, size_t ws_size,
                              hipStream_t stream) {
  (void)in_sizes; (void)n_in; (void)out_size; (void)ws_size;
  const float* adj  = (const float*)d_in[0];
  const float* x    = (const float*)d_in[1];
  const float* cWs0 = (const float*)d_in[2];
  const float* cbs0 = (const float*)d_in[3];
  const float* cWe0 = (const float*)d_in[4];
  const float* cbe0 = (const float*)d_in[5];
  const float* cg0  = (const float*)d_in[6];
  const float* cb0  = (const float*)d_in[7];
  const float* cWs1 = (const float*)d_in[8];
  const float* cbs1 = (const float*)d_in[9];
  const float* cWe1 = (const float*)d_in[10];
  const float* cbe1 = (const float*)d_in[11];
  const float* cg1  = (const float*)d_in[12];
  const float* cb1  = (const float*)d_in[13];
  const float* lW0  = (const float*)d_in[14];
  const float* lb0  = (const float*)d_in[15];
  const float* lg0  = (const float*)d_in[16];
  const float* lbb0 = (const float*)d_in[17];
  const float* fW   = (const float*)d_in[18];
  const float* fb   = (const float*)d_in[19];
  float* out = (float*)d_out;

  // ---- workspace layout ----
  char* p = (char*)d_ws;
  float* stats = (float*)p;                     p += 1024;
  unsigned short* Wg0  = (unsigned short*)p;    p += 256 * 96 * 2;
  unsigned short* Wfb  = (unsigned short*)p;    p += 32 * 512 * 2;
  unsigned short* Wcat = (unsigned short*)p;    p += 256 * 1280 * 2;
  unsigned short* Wl   = (unsigned short*)p;    p += 512 * 256 * 2;
  float* part0 = (float*)p;                     p += 2048 * 76 * 4;
  float* part1 = (float*)p;                     p += 2048 * 76 * 4;
  float* part2 = (float*)p;                     p += 1216 * 76 * 4;
  unsigned short* g0   = (unsigned short*)p;    p += (size_t)M_ * 256 * 2;
  unsigned short* h2   = (unsigned short*)p;    p += (size_t)M_ * 256 * 2;
  unsigned short* g2   = (unsigned short*)p;    // 79.7MB

  float* st0 = stats;
  float* st1 = stats + 76;
  float* st2 = stats + 152;

  k_build_wg0<<<96, 256, 0, stream>>>(cWs0, cbs0, cWe0, cbe0, Wg0);
  k_build_wcat<<<1280, 256, 0, stream>>>(cWs1, cWe1, Wcat);
  k_build_wl<<<512, 256, 0, stream>>>(lW0, Wl);
  k_build_wf<<<64, 256, 0, stream>>>(fW, Wfb);

  // layer 0 (full MFMA; writes g0 raw + stats partials)
  k_gconv0<<<2048, 256, 0, stream>>>(adj, x, Wg0, g0, part0);
  k_gred<<<76, 256, 0, stream>>>(part0, 2048, st0);

  // layer 1 fused: P-trick, no Y materialization
  k_l1f<<<2048, 256, 0, stream>>>(adj, g0, Wcat, st0, cg0, cb0, cbs1, cbe1, h2, part1);
  k_gred<<<76, 256, 0, stream>>>(part1, 2048, st1);

  // layer 2: g2 = BN1ReLU(h2) * Wl^T + lb0  (+ stats partials)
  k_gemm<true, true><<<dim3(608, 2), 512, 0, stream>>>(
      h2, Wl, lb0, st1, cg1, cb1, 2048.f * 256.f, g2, 512, part2);
  k_gred<<<76, 256, 0, stream>>>(part2, 1216, st2);

  // final
  k_final<<<2048, 256, 0, stream>>>(g2, x, Wfb, fb, st2, lg0, lbb0, out);
}